// Round 1
// baseline (312.846 us; speedup 1.0000x reference)
//
#include <hip/hip_runtime.h>

// Problem: N=131072 rows, D=128 (graph_emb cols), O=256 (errors cols).
// out = -sum_j | sum_i errors[i,j] * (g0[i] - mean(g0)) |   with g0 = graph_emb[:,0]
// Identity used: errors-mean term cancels because sum_i (g0[i]-mean(g0)) == 0.
//
// Single streaming pass over errors (128 MB, the dominant traffic):
//   A[j] = sum_i errors[i,j]*g0[i], B[j] = sum_i errors[i,j], G = sum_i g0[i]
// then col_sums[j] = A[j] - (G/N)*B[j].

#define NB 1024  // blocks for main kernel (4/CU)

__global__ __launch_bounds__(256) void cov_main_kernel(
    const float* __restrict__ errors,     // N x O
    const float* __restrict__ graph_emb,  // N x D
    float* __restrict__ acc,              // [0..255]=A, [256..511]=B, [512]=G
    int N, int D, int O)
{
    const int tid = threadIdx.x;
    const int g   = tid >> 6;   // wave id within block, 0..3 -> row offset
    const int l   = tid & 63;   // lane -> 4 columns l*4..l*4+3
    const int vecPerRow = O >> 2;  // 64 (float4 per row)

    const float4* __restrict__ err4 = (const float4*)errors;

    float a0 = 0.f, a1 = 0.f, a2 = 0.f, a3 = 0.f;  // A partials (4 cols)
    float b0 = 0.f, b1 = 0.f, b2 = 0.f, b3 = 0.f;  // B partials
    float gsum = 0.f;                               // G partial (lane 0 only)

    const int nRG = N >> 2;  // row-groups of 4 rows
    #pragma unroll 4
    for (int rg = blockIdx.x; rg < nRG; rg += NB) {
        const int row = (rg << 2) + g;
        const float gv = graph_emb[row * D];           // wave-uniform broadcast
        const float4 e = err4[row * vecPerRow + l];    // coalesced 16B/lane
        a0 = fmaf(e.x, gv, a0);
        a1 = fmaf(e.y, gv, a1);
        a2 = fmaf(e.z, gv, a2);
        a3 = fmaf(e.w, gv, a3);
        b0 += e.x; b1 += e.y; b2 += e.z; b3 += e.w;
        if (l == 0) gsum += gv;
    }

    // Cross-wave reduction: 4 waves hold the same 256 columns for different rows.
    __shared__ float sA[256 * 4];
    __shared__ float sB[256 * 4];
    __shared__ float sG[4];
    sA[tid * 4 + 0] = a0; sA[tid * 4 + 1] = a1; sA[tid * 4 + 2] = a2; sA[tid * 4 + 3] = a3;
    sB[tid * 4 + 0] = b0; sB[tid * 4 + 1] = b1; sB[tid * 4 + 2] = b2; sB[tid * 4 + 3] = b3;
    if (l == 0) sG[g] = gsum;
    __syncthreads();

    if (tid < 64) {
        float ra0 = 0.f, ra1 = 0.f, ra2 = 0.f, ra3 = 0.f;
        float rb0 = 0.f, rb1 = 0.f, rb2 = 0.f, rb3 = 0.f;
        #pragma unroll
        for (int gg = 0; gg < 4; ++gg) {
            const int base = (gg * 64 + tid) * 4;
            ra0 += sA[base + 0]; ra1 += sA[base + 1]; ra2 += sA[base + 2]; ra3 += sA[base + 3];
            rb0 += sB[base + 0]; rb1 += sB[base + 1]; rb2 += sB[base + 2]; rb3 += sB[base + 3];
        }
        const int c = tid * 4;
        atomicAdd(&acc[c + 0], ra0);
        atomicAdd(&acc[c + 1], ra1);
        atomicAdd(&acc[c + 2], ra2);
        atomicAdd(&acc[c + 3], ra3);
        atomicAdd(&acc[256 + c + 0], rb0);
        atomicAdd(&acc[256 + c + 1], rb1);
        atomicAdd(&acc[256 + c + 2], rb2);
        atomicAdd(&acc[256 + c + 3], rb3);
    }
    if (tid == 0) {
        atomicAdd(&acc[512], sG[0] + sG[1] + sG[2] + sG[3]);
    }
}

__global__ __launch_bounds__(256) void cov_final_kernel(
    const float* __restrict__ acc, float* __restrict__ out, int N, int O)
{
    const int tid = threadIdx.x;
    const float mu = acc[512] / (float)N;
    float v = 0.f;
    if (tid < O) {
        const float cs = acc[tid] - mu * acc[256 + tid];
        v = fabsf(cs);
    }
    // wave64 shuffle reduce
    #pragma unroll
    for (int off = 32; off > 0; off >>= 1)
        v += __shfl_down(v, off, 64);
    __shared__ float sW[4];
    if ((tid & 63) == 0) sW[tid >> 6] = v;
    __syncthreads();
    if (tid == 0) {
        out[0] = -(sW[0] + sW[1] + sW[2] + sW[3]);
    }
}

extern "C" void kernel_launch(void* const* d_in, const int* in_sizes, int n_in,
                              void* d_out, int out_size, void* d_ws, size_t ws_size,
                              hipStream_t stream) {
    // inputs: 0=targets(N), 1=out0(1), 2=out1(1), 3=graph_emb(N*D), 4=errors(N*O)
    const int N = in_sizes[0];
    const int D = in_sizes[3] / N;
    const int O = in_sizes[4] / N;
    const float* graph_emb = (const float*)d_in[3];
    const float* errors    = (const float*)d_in[4];
    float* acc = (float*)d_ws;  // 513 floats

    hipMemsetAsync(acc, 0, 513 * sizeof(float), stream);
    cov_main_kernel<<<NB, 256, 0, stream>>>(errors, graph_emb, acc, N, D, O);
    cov_final_kernel<<<1, 256, 0, stream>>>(acc, (float*)d_out, N, O);
}

// Round 2
// 240.249 us; speedup vs baseline: 1.3022x; 1.3022x over previous
//
#include <hip/hip_runtime.h>

// out = -sum_j | sum_i errors[i,j] * (g0[i] - mean(g0)) |,  g0 = graph_emb[:,0]
// (errors-mean term cancels since sum_i (g0[i]-mean(g0)) == 0)
//
// Stage 1: stream errors (128 MB), accumulate per-block partials:
//          A[j] = sum e*g0, B[j] = sum e, G = sum g0  -> partials[col][block]
// Stage 2: 513 blocks reduce partials rows -> acc[513]
// Stage 3: col_sums[j] = A[j] - (G/N)*B[j]; out = -sum |col_sums|
// NO atomics anywhere (R1's 525k same-address atomicAdds serialized ~100us).

#define NB 1024   // stage-1 blocks
#define BT 512    // stage-1 threads/block (8 waves) -> 32 waves/CU

__global__ __launch_bounds__(BT) void cov_main_kernel(
    const float* __restrict__ errors,     // N x O
    const float* __restrict__ graph_emb,  // N x D
    float* __restrict__ partials,         // [513][NB]
    int N, int D, int O)
{
    const int tid = threadIdx.x;
    const int g   = tid >> 6;        // wave id 0..7 -> row offset within group
    const int l   = tid & 63;        // lane -> 4 columns l*4..l*4+3
    const int vecPerRow = O >> 2;    // 64

    const float4* __restrict__ err4 = (const float4*)errors;

    float a0 = 0.f, a1 = 0.f, a2 = 0.f, a3 = 0.f;
    float b0 = 0.f, b1 = 0.f, b2 = 0.f, b3 = 0.f;
    float gsum = 0.f;

    const int nRG = N >> 3;          // groups of 8 rows (one per wave)
    #pragma unroll 4
    for (int rg = blockIdx.x; rg < nRG; rg += NB) {
        const int row = (rg << 3) + g;
        const float gv = graph_emb[row * D];         // wave-uniform broadcast
        const float4 e = err4[row * vecPerRow + l];  // coalesced 16B/lane
        a0 = fmaf(e.x, gv, a0);
        a1 = fmaf(e.y, gv, a1);
        a2 = fmaf(e.z, gv, a2);
        a3 = fmaf(e.w, gv, a3);
        b0 += e.x; b1 += e.y; b2 += e.z; b3 += e.w;
        if (l == 0) gsum += gv;
    }

    // Cross-wave reduction; lane-contiguous LDS layout (conflict-free).
    __shared__ float sA[4 * BT];   // [k][tid]
    __shared__ float sB[4 * BT];
    __shared__ float sG[8];
    sA[0 * BT + tid] = a0; sA[1 * BT + tid] = a1;
    sA[2 * BT + tid] = a2; sA[3 * BT + tid] = a3;
    sB[0 * BT + tid] = b0; sB[1 * BT + tid] = b1;
    sB[2 * BT + tid] = b2; sB[3 * BT + tid] = b3;
    if (l == 0) sG[g] = gsum;
    __syncthreads();

    if (tid < 64) {
        float ra0 = 0.f, ra1 = 0.f, ra2 = 0.f, ra3 = 0.f;
        float rb0 = 0.f, rb1 = 0.f, rb2 = 0.f, rb3 = 0.f;
        #pragma unroll
        for (int gg = 0; gg < 8; ++gg) {
            const int idx = gg * 64 + tid;
            ra0 += sA[0 * BT + idx]; ra1 += sA[1 * BT + idx];
            ra2 += sA[2 * BT + idx]; ra3 += sA[3 * BT + idx];
            rb0 += sB[0 * BT + idx]; rb1 += sB[1 * BT + idx];
            rb2 += sB[2 * BT + idx]; rb3 += sB[3 * BT + idx];
        }
        const int b = blockIdx.x;
        const int c = tid * 4;
        partials[(c + 0) * NB + b] = ra0;
        partials[(c + 1) * NB + b] = ra1;
        partials[(c + 2) * NB + b] = ra2;
        partials[(c + 3) * NB + b] = ra3;
        partials[(256 + c + 0) * NB + b] = rb0;
        partials[(256 + c + 1) * NB + b] = rb1;
        partials[(256 + c + 2) * NB + b] = rb2;
        partials[(256 + c + 3) * NB + b] = rb3;
    }
    if (tid == 0) {
        float s = 0.f;
        #pragma unroll
        for (int gg = 0; gg < 8; ++gg) s += sG[gg];
        partials[512 * NB + blockIdx.x] = s;
    }
}

// Block c reduces partials[c][0..NB-1] -> acc[c]. 256 threads, 1 float4 each.
__global__ __launch_bounds__(256) void cov_reduce_kernel(
    const float* __restrict__ partials, float* __restrict__ acc)
{
    const int c = blockIdx.x;
    const int tid = threadIdx.x;
    const float4 p = ((const float4*)(partials + c * NB))[tid];
    float v = p.x + p.y + p.z + p.w;
    #pragma unroll
    for (int off = 32; off > 0; off >>= 1)
        v += __shfl_down(v, off, 64);
    __shared__ float sW[4];
    if ((tid & 63) == 0) sW[tid >> 6] = v;
    __syncthreads();
    if (tid == 0) acc[c] = sW[0] + sW[1] + sW[2] + sW[3];
}

__global__ __launch_bounds__(256) void cov_final_kernel(
    const float* __restrict__ acc, float* __restrict__ out, int N, int O)
{
    const int tid = threadIdx.x;
    const float mu = acc[512] / (float)N;
    float v = 0.f;
    if (tid < O) {
        const float cs = acc[tid] - mu * acc[256 + tid];
        v = fabsf(cs);
    }
    #pragma unroll
    for (int off = 32; off > 0; off >>= 1)
        v += __shfl_down(v, off, 64);
    __shared__ float sW[4];
    if ((tid & 63) == 0) sW[tid >> 6] = v;
    __syncthreads();
    if (tid == 0) out[0] = -(sW[0] + sW[1] + sW[2] + sW[3]);
}

extern "C" void kernel_launch(void* const* d_in, const int* in_sizes, int n_in,
                              void* d_out, int out_size, void* d_ws, size_t ws_size,
                              hipStream_t stream) {
    // inputs: 0=targets(N), 1=out0(1), 2=out1(1), 3=graph_emb(N*D), 4=errors(N*O)
    const int N = in_sizes[0];
    const int D = in_sizes[3] / N;
    const int O = in_sizes[4] / N;
    const float* graph_emb = (const float*)d_in[3];
    const float* errors    = (const float*)d_in[4];

    float* partials = (float*)d_ws;                 // 513 * NB floats (~2.1 MB)
    float* acc      = partials + 513 * NB;          // 513 floats

    cov_main_kernel<<<NB, BT, 0, stream>>>(errors, graph_emb, partials, N, D, O);
    cov_reduce_kernel<<<513, 256, 0, stream>>>(partials, acc);
    cov_final_kernel<<<1, 256, 0, stream>>>(acc, (float*)d_out, N, O);
}